// Round 1
// baseline (2509.064 us; speedup 1.0000x reference)
//
#include <hip/hip_runtime.h>
#include <math.h>

// Problem constants
#define B_  64
#define N_  393
#define C_  768
#define H_  12
#define HD_ 64
#define P_  197
#define NB_ 8
#define SCALE_ 0.125f

// ---------------------------------------------------------------------------
// Kernel 1: prep — q = q_learned + pos_embed (P,C); lookup (H,8) per p;
//           biasmat[h][p][pj] = lookup[h][rp_bucket[p][pj]]
// grid: P_, block: 256
// ---------------------------------------------------------------------------
__global__ __launch_bounds__(256) void prep_kernel(
    const float* __restrict__ q_learned,
    const float* __restrict__ pos_embed,
    const float* __restrict__ rpe_w,     // [HD_][NB_]
    const int*   __restrict__ rp_bucket, // [P_][P_]
    float* __restrict__ qbuf,            // [P_][C_]
    float* __restrict__ biasmat)         // [H_][P_][P_]
{
    __shared__ float q_s[C_];
    __shared__ float lk_s[H_ * NB_];
    const int p = blockIdx.x;
    const int t = threadIdx.x;

    for (int c = t; c < C_; c += 256) {
        float v = q_learned[c] + pos_embed[p * C_ + c];
        q_s[c] = v;
        qbuf[p * C_ + c] = v;
    }
    __syncthreads();

    if (t < H_ * NB_) {
        int h = t / NB_, u = t % NB_;
        float s = 0.f;
        #pragma unroll 8
        for (int d = 0; d < HD_; ++d)
            s = fmaf(q_s[h * HD_ + d], rpe_w[d * NB_ + u], s);
        lk_s[t] = s;
    }
    __syncthreads();

    for (int idx = t; idx < H_ * P_; idx += 256) {
        int h = idx / P_, pj = idx % P_;
        int bucket = rp_bucket[p * P_ + pj];
        biasmat[((size_t)h * P_ + p) * P_ + pj] = lk_s[h * NB_ + bucket];
    }
}

// ---------------------------------------------------------------------------
// Kernel 2: K,V = x @ wk.T, x @ wv.T   (NT GEMM, dual output, shared A tile)
// A: [M=25152][768], W: [768][768]. BM=BN=64, BK=16, 256 thr, 4x4 micro-tile.
// grid: (M/64, 768/64)
// ---------------------------------------------------------------------------
__global__ __launch_bounds__(256) void kv_gemm(
    const float* __restrict__ x,
    const float* __restrict__ wk,
    const float* __restrict__ wv,
    float* __restrict__ Kout,
    float* __restrict__ Vout)
{
    __shared__ float As[16][64];
    __shared__ float Bs[16][64];
    __shared__ float Cs[16][64];
    const int m0 = blockIdx.x * 64;
    const int n0 = blockIdx.y * 64;
    const int t  = threadIdx.x;
    const int lr = t >> 2;          // 0..63 load row
    const int lk = (t & 3) * 4;     // 0,4,8,12
    const int ty = t >> 4;          // 0..15
    const int tx = t & 15;          // 0..15

    float aK[4][4] = {{0.f}};
    float aV[4][4] = {{0.f}};

    for (int k0 = 0; k0 < C_; k0 += 16) {
        float4 av = *(const float4*)(x  + (size_t)(m0 + lr) * C_ + k0 + lk);
        float4 bv = *(const float4*)(wk + (size_t)(n0 + lr) * C_ + k0 + lk);
        float4 cv = *(const float4*)(wv + (size_t)(n0 + lr) * C_ + k0 + lk);
        __syncthreads();
        As[lk + 0][lr] = av.x; As[lk + 1][lr] = av.y;
        As[lk + 2][lr] = av.z; As[lk + 3][lr] = av.w;
        Bs[lk + 0][lr] = bv.x; Bs[lk + 1][lr] = bv.y;
        Bs[lk + 2][lr] = bv.z; Bs[lk + 3][lr] = bv.w;
        Cs[lk + 0][lr] = cv.x; Cs[lk + 1][lr] = cv.y;
        Cs[lk + 2][lr] = cv.z; Cs[lk + 3][lr] = cv.w;
        __syncthreads();
        #pragma unroll
        for (int k = 0; k < 16; ++k) {
            float4 a = *(const float4*)&As[k][ty * 4];
            float4 b = *(const float4*)&Bs[k][tx * 4];
            float4 c = *(const float4*)&Cs[k][tx * 4];
            const float ar[4] = {a.x, a.y, a.z, a.w};
            const float br[4] = {b.x, b.y, b.z, b.w};
            const float cr[4] = {c.x, c.y, c.z, c.w};
            #pragma unroll
            for (int i = 0; i < 4; ++i)
                #pragma unroll
                for (int j = 0; j < 4; ++j) {
                    aK[i][j] = fmaf(ar[i], br[j], aK[i][j]);
                    aV[i][j] = fmaf(ar[i], cr[j], aV[i][j]);
                }
        }
    }
    #pragma unroll
    for (int i = 0; i < 4; ++i) {
        size_t row = (size_t)(m0 + ty * 4 + i) * C_ + n0 + tx * 4;
        *(float4*)(Kout + row) = make_float4(aK[i][0], aK[i][1], aK[i][2], aK[i][3]);
        *(float4*)(Vout + row) = make_float4(aV[i][0], aV[i][1], aV[i][2], aV[i][3]);
    }
}

// ---------------------------------------------------------------------------
// Kernel 3: fused attention. One block = (b, h, 16-row p-tile).
// Scores kept in LDS (16 x 400), two-pass softmax, then PV.
// K staged transposed [d][j] stride 66 (bank-conflict pad); V row-major [j][d].
// grid: (ceil(P/16)=13, H, B), block 256
// ---------------------------------------------------------------------------
__global__ __launch_bounds__(256) void attn_kernel(
    const float* __restrict__ qbuf,    // [P_][C_]
    const float* __restrict__ Kin,     // [B_][N_][C_]
    const float* __restrict__ Vin,     // [B_][N_][C_]
    const float* __restrict__ biasmat, // [H_][P_][P_]
    float* __restrict__ Obuf)          // [B_][P_][C_]
{
    __shared__ float q_s[16][64];      // 4 KB
    __shared__ float kv[64 * 66];      // 16.9 KB (K^T stride 66; V stride 64)
    __shared__ float sc[16][400];      // 25.6 KB (393 cols used)
    __shared__ float rinv[16];

    const int pt = blockIdx.x, h = blockIdx.y, b = blockIdx.z;
    const int p0 = pt * 16;
    const int t  = threadIdx.x;

    // load q tile (zero-fill invalid rows)
    {
        int r = t >> 4, c4 = (t & 15) * 4;
        float4 v = make_float4(0.f, 0.f, 0.f, 0.f);
        if (p0 + r < P_)
            v = *(const float4*)(qbuf + (size_t)(p0 + r) * C_ + h * HD_ + c4);
        *(float4*)&q_s[r][c4] = v;
    }

    const int rr = (t >> 5) * 2;   // row base (0..14, step 2)
    const int cc = (t & 31) * 2;   // col base (0..62, step 2)

    // ---------------- scores ----------------
    for (int n0 = 0; n0 < N_; n0 += 64) {
        __syncthreads();   // previous tile fully consumed (also covers q_s load)
        for (int i = t; i < 64 * 16; i += 256) {
            int j = i >> 4, c4 = (i & 15) * 4;
            float4 v = make_float4(0.f, 0.f, 0.f, 0.f);
            if (n0 + j < N_)
                v = *(const float4*)(Kin + ((size_t)b * N_ + n0 + j) * C_ + h * HD_ + c4);
            kv[(c4 + 0) * 66 + j] = v.x;
            kv[(c4 + 1) * 66 + j] = v.y;
            kv[(c4 + 2) * 66 + j] = v.z;
            kv[(c4 + 3) * 66 + j] = v.w;
        }
        __syncthreads();

        float acc[2][2] = {{0.f}};
        #pragma unroll
        for (int d4 = 0; d4 < HD_; d4 += 4) {
            float4 qv0 = *(const float4*)&q_s[rr + 0][d4];
            float4 qv1 = *(const float4*)&q_s[rr + 1][d4];
            const float q0r[4] = {qv0.x, qv0.y, qv0.z, qv0.w};
            const float q1r[4] = {qv1.x, qv1.y, qv1.z, qv1.w};
            #pragma unroll
            for (int dd = 0; dd < 4; ++dd) {
                float2 k2 = *(const float2*)&kv[(d4 + dd) * 66 + cc];
                acc[0][0] = fmaf(q0r[dd], k2.x, acc[0][0]);
                acc[0][1] = fmaf(q0r[dd], k2.y, acc[0][1]);
                acc[1][0] = fmaf(q1r[dd], k2.x, acc[1][0]);
                acc[1][1] = fmaf(q1r[dd], k2.y, acc[1][1]);
            }
        }
        #pragma unroll
        for (int i = 0; i < 2; ++i) {
            int r = rr + i, p = p0 + r;
            if (p < P_) {
                #pragma unroll
                for (int j = 0; j < 2; ++j) {
                    int jj = n0 + cc + j;
                    if (jj < N_) {
                        int jm;
                        if (jj == 0) jm = 0;
                        else { jm = jj - 1; if (jm >= 196) jm -= 196; jm += 1; }
                        float bias = biasmat[((size_t)h * P_ + p) * P_ + jm];
                        sc[r][jj] = fmaf(acc[i][j], SCALE_, bias);
                    }
                }
            }
        }
    }
    __syncthreads();

    // ---------------- softmax (16 rows x 16 lanes each) ----------------
    {
        int r = t >> 4, l16 = t & 15;
        float m = -1e30f;
        for (int j = l16; j < N_; j += 16) m = fmaxf(m, sc[r][j]);
        #pragma unroll
        for (int w = 1; w < 16; w <<= 1) m = fmaxf(m, __shfl_xor(m, w, 64));
        float s = 0.f;
        for (int j = l16; j < N_; j += 16) {
            float e = __expf(sc[r][j] - m);
            sc[r][j] = e;
            s += e;
        }
        #pragma unroll
        for (int w = 1; w < 16; w <<= 1) s += __shfl_xor(s, w, 64);
        if (l16 == 0) rinv[r] = 1.0f / s;
    }

    // ---------------- PV ----------------
    float oa[2][2] = {{0.f}};
    for (int n0 = 0; n0 < N_; n0 += 64) {
        __syncthreads();   // sc normalize done / previous V consumed
        for (int i = t; i < 64 * 16; i += 256) {
            int j = i >> 4, c4 = (i & 15) * 4;
            float4 v = make_float4(0.f, 0.f, 0.f, 0.f);
            if (n0 + j < N_)
                v = *(const float4*)(Vin + ((size_t)b * N_ + n0 + j) * C_ + h * HD_ + c4);
            *(float4*)&kv[j * 64 + c4] = v;
        }
        __syncthreads();
        const int nn = min(64, N_ - n0);
        for (int j = 0; j < nn; ++j) {
            float2 v2 = *(const float2*)&kv[j * 64 + cc];
            float pv0 = sc[rr + 0][n0 + j];
            float pv1 = sc[rr + 1][n0 + j];
            oa[0][0] = fmaf(pv0, v2.x, oa[0][0]);
            oa[0][1] = fmaf(pv0, v2.y, oa[0][1]);
            oa[1][0] = fmaf(pv1, v2.x, oa[1][0]);
            oa[1][1] = fmaf(pv1, v2.y, oa[1][1]);
        }
    }
    #pragma unroll
    for (int i = 0; i < 2; ++i) {
        int p = p0 + rr + i;
        if (p < P_) {
            float inv = rinv[rr + i];
            float2 o2 = make_float2(oa[i][0] * inv, oa[i][1] * inv);
            *(float2*)(Obuf + ((size_t)b * P_ + p) * C_ + h * HD_ + cc) = o2;
        }
    }
}

// ---------------------------------------------------------------------------
// Kernel 4: out = A @ proj_w.T + proj_b   (NT GEMM + bias)
// A: [M=12608][768]. grid: (M/64, 768/64)
// ---------------------------------------------------------------------------
__global__ __launch_bounds__(256) void proj_gemm(
    const float* __restrict__ A,
    const float* __restrict__ W,
    const float* __restrict__ bias,
    float* __restrict__ Cout)
{
    __shared__ float As[16][64];
    __shared__ float Bs[16][64];
    const int m0 = blockIdx.x * 64;
    const int n0 = blockIdx.y * 64;
    const int t  = threadIdx.x;
    const int lr = t >> 2;
    const int lk = (t & 3) * 4;
    const int ty = t >> 4;
    const int tx = t & 15;

    float acc[4][4] = {{0.f}};

    for (int k0 = 0; k0 < C_; k0 += 16) {
        float4 av = *(const float4*)(A + (size_t)(m0 + lr) * C_ + k0 + lk);
        float4 bv = *(const float4*)(W + (size_t)(n0 + lr) * C_ + k0 + lk);
        __syncthreads();
        As[lk + 0][lr] = av.x; As[lk + 1][lr] = av.y;
        As[lk + 2][lr] = av.z; As[lk + 3][lr] = av.w;
        Bs[lk + 0][lr] = bv.x; Bs[lk + 1][lr] = bv.y;
        Bs[lk + 2][lr] = bv.z; Bs[lk + 3][lr] = bv.w;
        __syncthreads();
        #pragma unroll
        for (int k = 0; k < 16; ++k) {
            float4 a = *(const float4*)&As[k][ty * 4];
            float4 b = *(const float4*)&Bs[k][tx * 4];
            const float ar[4] = {a.x, a.y, a.z, a.w};
            const float br[4] = {b.x, b.y, b.z, b.w};
            #pragma unroll
            for (int i = 0; i < 4; ++i)
                #pragma unroll
                for (int j = 0; j < 4; ++j)
                    acc[i][j] = fmaf(ar[i], br[j], acc[i][j]);
        }
    }
    float4 bb = *(const float4*)(bias + n0 + tx * 4);
    const float br[4] = {bb.x, bb.y, bb.z, bb.w};
    #pragma unroll
    for (int i = 0; i < 4; ++i) {
        size_t row = (size_t)(m0 + ty * 4 + i) * C_ + n0 + tx * 4;
        *(float4*)(Cout + row) = make_float4(acc[i][0] + br[0], acc[i][1] + br[1],
                                             acc[i][2] + br[2], acc[i][3] + br[3]);
    }
}

// ---------------------------------------------------------------------------
extern "C" void kernel_launch(void* const* d_in, const int* in_sizes, int n_in,
                              void* d_out, int out_size, void* d_ws, size_t ws_size,
                              hipStream_t stream)
{
    const float* x         = (const float*)d_in[0];
    const float* q_learned = (const float*)d_in[1];
    const float* pos_embed = (const float*)d_in[2];
    const float* wk        = (const float*)d_in[3];
    const float* wv        = (const float*)d_in[4];
    const float* rpe_w     = (const float*)d_in[5];
    const float* proj_w    = (const float*)d_in[6];
    const float* proj_b    = (const float*)d_in[7];
    const int*   rp_bucket = (const int*)d_in[8];
    float* out = (float*)d_out;

    // Workspace carve-up (floats). Total ~48.94M floats ~ 187 MB.
    float* ws      = (float*)d_ws;
    float* qbuf    = ws;                                   // P_*C_      = 151296
    float* biasmat = qbuf + (size_t)P_ * C_;               // H_*P_*P_   = 465708
    float* Kbuf    = biasmat + (size_t)H_ * P_ * P_;       // B_*N_*C_   = 19316736
    float* Vbuf    = Kbuf + (size_t)B_ * N_ * C_;
    float* Obuf    = Vbuf + (size_t)B_ * N_ * C_;          // B_*P_*C_   = 9683968

    prep_kernel<<<P_, 256, 0, stream>>>(q_learned, pos_embed, rpe_w, rp_bucket,
                                        qbuf, biasmat);

    dim3 gkv((B_ * N_) / 64, C_ / 64);   // 393 x 12
    kv_gemm<<<gkv, 256, 0, stream>>>(x, wk, wv, Kbuf, Vbuf);

    dim3 gat((P_ + 15) / 16, H_, B_);    // 13 x 12 x 64
    attn_kernel<<<gat, 256, 0, stream>>>(qbuf, Kbuf, Vbuf, biasmat, Obuf);

    dim3 gpr((B_ * P_) / 64, C_ / 64);   // 197 x 12
    proj_gemm<<<gpr, 256, 0, stream>>>(Obuf, proj_w, proj_b, out);
}

// Round 2
// 357.739 us; speedup vs baseline: 7.0137x; 7.0137x over previous
//
#include <hip/hip_runtime.h>

typedef unsigned short u16;
typedef short bf16x8 __attribute__((ext_vector_type(8)));
typedef float f32x4 __attribute__((ext_vector_type(4)));

#define B_   64
#define N_   393
#define C_   768
#define H_   12
#define HD_  64
#define P_   197
#define NPAD 416
#define PPAD 208
#define M_KV (B_ * N_)   // 25152
#define M_PR (B_ * P_)   // 12608
#define SCALE_ 0.125f

__device__ __forceinline__ u16 f2bf(float f) {
    unsigned u = __float_as_uint(f);
    return (u16)((u + 0x7FFFu + ((u >> 16) & 1u)) >> 16);
}

// ---------------------------------------------------------------------------
// fp32 -> bf16 conversion (vectorized, n % 4 == 0)
// ---------------------------------------------------------------------------
__global__ __launch_bounds__(256) void f2bf_kernel(const float* __restrict__ in,
                                                   u16* __restrict__ out, int n4) {
    int i = blockIdx.x * 256 + threadIdx.x;
    if (i < n4) {
        float4 v = ((const float4*)in)[i];
        u16 o[4] = {f2bf(v.x), f2bf(v.y), f2bf(v.z), f2bf(v.w)};
        *(uint2*)(out + i * 4) = *(uint2*)o;
    }
}

// ---------------------------------------------------------------------------
// prep1: q = q_learned + pos_embed -> qh (bf16 [P][C]); lk[h][p][8] fp32
// grid: P_, block 256
// ---------------------------------------------------------------------------
__global__ __launch_bounds__(256) void prep1_kernel(
    const float* __restrict__ q_learned, const float* __restrict__ pos_embed,
    const float* __restrict__ rpe_w, u16* __restrict__ qh, float* __restrict__ lk)
{
    __shared__ float q_s[C_];
    const int p = blockIdx.x, t = threadIdx.x;
    for (int c = t; c < C_; c += 256) {
        float v = q_learned[c] + pos_embed[p * C_ + c];
        q_s[c] = v;
        qh[p * C_ + c] = f2bf(v);
    }
    __syncthreads();
    if (t < H_ * 8) {
        int h = t >> 3, u = t & 7;
        float s = 0.f;
        #pragma unroll 8
        for (int d = 0; d < HD_; ++d)
            s = fmaf(q_s[h * HD_ + d], rpe_w[d * 8 + u], s);
        lk[(h * P_ + p) * 8 + u] = s;
    }
}

// ---------------------------------------------------------------------------
// prep2: biasT[h][j][p] = lk[h][p][rp_bucket[p][jm(j)]]  (fp32, p padded 208)
// grid: H_*N_ blocks (h = bx/393, j = bx%393), block 256 (p = t, t < 208)
// ---------------------------------------------------------------------------
__global__ __launch_bounds__(256) void prep2_kernel(
    const float* __restrict__ lk, const int* __restrict__ rp_bucket,
    float* __restrict__ biasT)
{
    int bx = blockIdx.x;
    int h = bx / N_, j = bx % N_;
    int t = threadIdx.x;
    if (t >= PPAD) return;
    int jm;
    if (j == 0) jm = 0;
    else { jm = j - 1; if (jm >= 196) jm -= 196; jm += 1; }
    float v = 0.f;
    if (t < P_) {
        int bucket = rp_bucket[t * P_ + jm];
        v = lk[(h * P_ + t) * 8 + bucket];
    }
    biasT[((size_t)h * NPAD + j) * PPAD + t] = v;
}

// ---------------------------------------------------------------------------
// Templated 128x128x64 bf16 MFMA GEMM:  C[M][ldc] = A[M][768] * Bw[ldc][768]^T
// Reg-staged LDS with XOR-swizzle (T2) for conflict-free ds_read_b128.
// grid: (ldc/128, ceil(M/128)), block 256 (4 waves, 2x2, 64x64 each)
// ---------------------------------------------------------------------------
template <bool F32OUT>
__global__ __launch_bounds__(256) void gemm_bf16(
    const u16* __restrict__ A, const u16* __restrict__ Bw,
    u16* __restrict__ Cb, float* __restrict__ Cf, const float* __restrict__ bias,
    int M, int ldc)
{
    __shared__ __align__(16) u16 As[128 * 64];
    __shared__ __align__(16) u16 Bs[128 * 64];
    const int n0 = blockIdx.x * 128, m0 = blockIdx.y * 128;
    const int t = threadIdx.x;
    const int w = t >> 6, l = t & 63;
    const int wr = w >> 1, wc = w & 1;
    const int l15 = l & 15, lg = l >> 4;
    const int Mc = M - 1;

    f32x4 acc[4][4];
    #pragma unroll
    for (int i = 0; i < 4; ++i)
        #pragma unroll
        for (int j = 0; j < 4; ++j) acc[i][j] = (f32x4){0.f, 0.f, 0.f, 0.f};

    // precomputed LDS read offsets (elem units)
    int aoff[4][2], boff[4][2];
    #pragma unroll
    for (int mf = 0; mf < 4; ++mf)
        #pragma unroll
        for (int kk = 0; kk < 2; ++kk) {
            int row = wr * 64 + mf * 16 + l15;
            int s = kk * 4 + lg;
            aoff[mf][kk] = row * 64 + ((s ^ (row & 7)) << 3);
            row = wc * 64 + mf * 16 + l15;
            boff[mf][kk] = row * 64 + ((s ^ (row & 7)) << 3);
        }
    // staging chunk geometry
    int srow[4], sslot[4], soff[4];
    #pragma unroll
    for (int i = 0; i < 4; ++i) {
        int c = t + 256 * i;
        srow[i] = c >> 3;
        sslot[i] = c & 7;
        soff[i] = srow[i] * 64 + ((sslot[i] ^ (srow[i] & 7)) << 3);
    }

    for (int ks = 0; ks < 12; ++ks) {
        const int k0 = ks * 64;
        bf16x8 ra[4], rb[4];
        #pragma unroll
        for (int i = 0; i < 4; ++i) {
            int am = m0 + srow[i]; if (am > Mc) am = Mc;
            ra[i] = *(const bf16x8*)(A + (size_t)am * 768 + k0 + sslot[i] * 8);
            rb[i] = *(const bf16x8*)(Bw + (size_t)(n0 + srow[i]) * 768 + k0 + sslot[i] * 8);
        }
        __syncthreads();
        #pragma unroll
        for (int i = 0; i < 4; ++i) {
            *(bf16x8*)(As + soff[i]) = ra[i];
            *(bf16x8*)(Bs + soff[i]) = rb[i];
        }
        __syncthreads();
        #pragma unroll
        for (int kk = 0; kk < 2; ++kk) {
            bf16x8 af[4], bf[4];
            #pragma unroll
            for (int mf = 0; mf < 4; ++mf) {
                af[mf] = *(const bf16x8*)(As + aoff[mf][kk]);
                bf[mf] = *(const bf16x8*)(Bs + boff[mf][kk]);
            }
            #pragma unroll
            for (int mf = 0; mf < 4; ++mf)
                #pragma unroll
                for (int nf = 0; nf < 4; ++nf)
                    acc[mf][nf] = __builtin_amdgcn_mfma_f32_16x16x32_bf16(
                        af[mf], bf[nf], acc[mf][nf], 0, 0, 0);
        }
    }

    #pragma unroll
    for (int mf = 0; mf < 4; ++mf) {
        #pragma unroll
        for (int nf = 0; nf < 4; ++nf) {
            int col = n0 + wc * 64 + nf * 16 + l15;
            float bb = 0.f;
            if (F32OUT) bb = bias[col];
            #pragma unroll
            for (int r = 0; r < 4; ++r) {
                int m = m0 + wr * 64 + mf * 16 + lg * 4 + r;
                if (m < M) {
                    if (F32OUT) Cf[(size_t)m * ldc + col] = acc[mf][nf][r] + bb;
                    else        Cb[(size_t)m * ldc + col] = f2bf(acc[mf][nf][r]);
                }
            }
        }
    }
}

// ---------------------------------------------------------------------------
// vtrans: Vt[b][h][d][j(416)] = KV[b*393+j][768 + h*64 + d]  (j>=393 -> 0)
// grid: B_*H_ blocks, 256 thr
// ---------------------------------------------------------------------------
__global__ __launch_bounds__(256) void vtrans_kernel(const u16* __restrict__ KV,
                                                     u16* __restrict__ Vt)
{
    const int bh = blockIdx.x;
    const int b = bh / H_, h = bh % H_;
    const int t = threadIdx.x, w = t >> 6, l = t & 63;
    const int d = w * 16 + (l >> 2);
    const int c = l & 3;
    const u16* src = KV + (size_t)b * N_ * 1536 + 768 + h * HD_ + d;
    u16* dst = Vt + (size_t)(bh * HD_ + d) * NPAD;
    for (int jb = 0; jb < NPAD; jb += 32) {
        int j0 = jb + c * 8;
        u16 v[8];
        #pragma unroll
        for (int i = 0; i < 8; ++i) {
            int j = j0 + i;
            v[i] = (j < N_) ? src[(size_t)j * 1536] : (u16)0;
        }
        *(bf16x8*)(dst + j0) = *(bf16x8*)v;
    }
}

// ---------------------------------------------------------------------------
// attention: one block = (b, h, 16-row p-tile). Q/K frags from global,
// scores in LDS fp32, wave-parallel softmax, P bf16 in LDS, PV from Vt.
// grid: (13, 12, 64), block 256
// ---------------------------------------------------------------------------
__global__ __launch_bounds__(256) void attn_mfma(
    const u16* __restrict__ qh, const u16* __restrict__ KV,
    const u16* __restrict__ Vt, const float* __restrict__ biasT,
    u16* __restrict__ Obuf)
{
    __shared__ __align__(16) float sc[16][424];
    __shared__ __align__(16) u16 pt[16][424];

    const int p0 = blockIdx.x * 16, h = blockIdx.y, b = blockIdx.z;
    const int t = threadIdx.x, w = t >> 6, l = t & 63;
    const int l15 = l & 15, lg = l >> 4;

    // Q fragments (clamped row)
    int prow = p0 + l15; if (prow > P_ - 1) prow = P_ - 1;
    const u16* qp = qh + (size_t)prow * C_ + h * HD_ + lg * 8;
    bf16x8 qf0 = *(const bf16x8*)(qp);
    bf16x8 qf1 = *(const bf16x8*)(qp + 32);

    // ---------------- QK^T + bias ----------------
    const u16* Kbase = KV + (size_t)b * N_ * 1536 + h * HD_ + lg * 8;
    for (int tt = w; tt < 25; tt += 4) {
        int n0 = tt * 16;
        int j = n0 + l15;
        const u16* kp = Kbase + (size_t)(n0 + l15) * 1536;
        bf16x8 kf0 = *(const bf16x8*)(kp);
        bf16x8 kf1 = *(const bf16x8*)(kp + 32);
        f32x4 acc = (f32x4){0.f, 0.f, 0.f, 0.f};
        acc = __builtin_amdgcn_mfma_f32_16x16x32_bf16(qf0, kf0, acc, 0, 0, 0);
        acc = __builtin_amdgcn_mfma_f32_16x16x32_bf16(qf1, kf1, acc, 0, 0, 0);
        int jc = j; if (jc > N_ - 1) jc = N_ - 1;
        float4 b4 = *(const float4*)(biasT + ((size_t)h * NPAD + jc) * PPAD + p0 + lg * 4);
        if (j < N_) {
            float bb[4] = {b4.x, b4.y, b4.z, b4.w};
            #pragma unroll
            for (int r = 0; r < 4; ++r)
                sc[lg * 4 + r][j] = fmaf(acc[r], SCALE_, bb[r]);
        }
    }
    __syncthreads();

    // ---------------- softmax (16 lanes per row) ----------------
    {
        int row = t >> 4, l16 = t & 15;
        float m = -1e30f;
        for (int j = l16; j < N_; j += 16) m = fmaxf(m, sc[row][j]);
        #pragma unroll
        for (int msk = 1; msk < 16; msk <<= 1) m = fmaxf(m, __shfl_xor(m, msk, 16));
        float s = 0.f;
        for (int j = l16; j < N_; j += 16) {
            float e = __expf(sc[row][j] - m);
            sc[row][j] = e;
            s += e;
        }
        #pragma unroll
        for (int msk = 1; msk < 16; msk <<= 1) s += __shfl_xor(s, msk, 16);
        float rinv = 1.0f / s;
        for (int j = l16; j < 424; j += 16)
            pt[row][j] = (j < N_) ? f2bf(sc[row][j] * rinv) : (u16)0;
    }
    __syncthreads();

    // ---------------- PV ----------------
    f32x4 o = (f32x4){0.f, 0.f, 0.f, 0.f};
    const u16* vbase = Vt + ((size_t)(b * H_ + h) * HD_ + w * 16 + l15) * NPAD + lg * 8;
    const u16* ptp = &pt[l15][lg * 8];
    #pragma unroll
    for (int ks = 0; ks < 13; ++ks) {
        bf16x8 pa = *(const bf16x8*)(ptp + ks * 32);
        bf16x8 vb = *(const bf16x8*)(vbase + ks * 32);
        o = __builtin_amdgcn_mfma_f32_16x16x32_bf16(pa, vb, o, 0, 0, 0);
    }
    #pragma unroll
    for (int r = 0; r < 4; ++r) {
        int p = p0 + lg * 4 + r;
        if (p < P_)
            Obuf[((size_t)b * P_ + p) * C_ + h * HD_ + w * 16 + l15] = f2bf(o[r]);
    }
}

// ---------------------------------------------------------------------------
extern "C" void kernel_launch(void* const* d_in, const int* in_sizes, int n_in,
                              void* d_out, int out_size, void* d_ws, size_t ws_size,
                              hipStream_t stream)
{
    const float* x         = (const float*)d_in[0];
    const float* q_learned = (const float*)d_in[1];
    const float* pos_embed = (const float*)d_in[2];
    const float* wk        = (const float*)d_in[3];
    const float* wv        = (const float*)d_in[4];
    const float* rpe_w     = (const float*)d_in[5];
    const float* proj_w    = (const float*)d_in[6];
    const float* proj_b    = (const float*)d_in[7];
    const int*   rp_bucket = (const int*)d_in[8];
    float* out = (float*)d_out;

    // workspace carve-up (byte offsets, 256-aligned)
    char* ws = (char*)d_ws;
    u16*   xh    = (u16*)(ws);                        // 38,633,472 B
    u16*   wkvh  = (u16*)(ws + 38633472);             //  2,359,296 B
    u16*   pwh   = (u16*)(ws + 40992768);             //  1,179,648 B
    u16*   qh    = (u16*)(ws + 42172416);             //    302,592 B
    float* lk    = (float*)(ws + 42475008);           //     75,776 B
    float* biasT = (float*)(ws + 42550784);           //  4,153,344 B
    u16*   KV    = (u16*)(ws + 46704128);             // 77,266,944 B
    u16*   Vt    = (u16*)(ws + 123971072);            // 40,894,464 B
    u16*   Obuf  = (u16*)(ws + 164865536);            // 19,365,888 B  (end ~184 MB)

    // 1. conversions
    f2bf_kernel<<<(19316736 / 4 + 255) / 256, 256, 0, stream>>>(x, xh, 19316736 / 4);
    f2bf_kernel<<<(589824 / 4 + 255) / 256, 256, 0, stream>>>(wk, wkvh, 589824 / 4);
    f2bf_kernel<<<(589824 / 4 + 255) / 256, 256, 0, stream>>>(wv, wkvh + 589824, 589824 / 4);
    f2bf_kernel<<<(589824 / 4 + 255) / 256, 256, 0, stream>>>(proj_w, pwh, 589824 / 4);

    // 2. prep
    prep1_kernel<<<P_, 256, 0, stream>>>(q_learned, pos_embed, rpe_w, qh, lk);
    prep2_kernel<<<H_ * N_, 256, 0, stream>>>(lk, rp_bucket, biasT);

    // 3. KV = x @ [wk;wv]^T  (bf16 out, [25152][1536])
    dim3 gkv(1536 / 128, (M_KV + 127) / 128);
    gemm_bf16<false><<<gkv, 256, 0, stream>>>(xh, wkvh, KV, nullptr, nullptr, M_KV, 1536);

    // 4. V transpose
    vtrans_kernel<<<B_ * H_, 256, 0, stream>>>(KV, Vt);

    // 5. attention
    dim3 gat((P_ + 15) / 16, H_, B_);
    attn_mfma<<<gat, 256, 0, stream>>>(qh, KV, Vt, biasT, Obuf);

    // 6. out = Obuf @ proj_w^T + proj_b  (fp32 out)
    dim3 gpr(768 / 128, (M_PR + 127) / 128);
    gemm_bf16<true><<<gpr, 256, 0, stream>>>(Obuf, pwh, nullptr, out, proj_b, M_PR, 768);
}

// Round 3
// 278.121 us; speedup vs baseline: 9.0215x; 1.2863x over previous
//
#include <hip/hip_runtime.h>

typedef unsigned short u16;
typedef short bf16x8 __attribute__((ext_vector_type(8)));
typedef float f32x4 __attribute__((ext_vector_type(4)));

#define B_   64
#define N_   393
#define C_   768
#define H_   12
#define HD_  64
#define P_   197
#define BIAS_N 416
#define PPAD 208
#define VTP  448
#define M_KV (B_ * N_)   // 25152
#define M_PR (B_ * P_)   // 12608
#define SCALE_ 0.125f

__device__ __forceinline__ u16 f2bf(float f) {
    unsigned u = __float_as_uint(f);
    return (u16)((u + 0x7FFFu + ((u >> 16) & 1u)) >> 16);
}

// ---------------------------------------------------------------------------
// fp32 -> bf16 conversion (vectorized, n % 4 == 0)
// ---------------------------------------------------------------------------
__global__ __launch_bounds__(256) void f2bf_kernel(const float* __restrict__ in,
                                                   u16* __restrict__ out, int n4) {
    int i = blockIdx.x * 256 + threadIdx.x;
    if (i < n4) {
        float4 v = ((const float4*)in)[i];
        u16 o[4] = {f2bf(v.x), f2bf(v.y), f2bf(v.z), f2bf(v.w)};
        *(uint2*)(out + i * 4) = *(uint2*)o;
    }
}

// ---------------------------------------------------------------------------
// prep1: q = q_learned + pos_embed -> qh (bf16 [P][C]); lk[h][p][8] fp32
// ---------------------------------------------------------------------------
__global__ __launch_bounds__(256) void prep1_kernel(
    const float* __restrict__ q_learned, const float* __restrict__ pos_embed,
    const float* __restrict__ rpe_w, u16* __restrict__ qh, float* __restrict__ lk)
{
    __shared__ float q_s[C_];
    const int p = blockIdx.x, t = threadIdx.x;
    for (int c = t; c < C_; c += 256) {
        float v = q_learned[c] + pos_embed[p * C_ + c];
        q_s[c] = v;
        qh[p * C_ + c] = f2bf(v);
    }
    __syncthreads();
    if (t < H_ * 8) {
        int h = t >> 3, u = t & 7;
        float s = 0.f;
        #pragma unroll 8
        for (int d = 0; d < HD_; ++d)
            s = fmaf(q_s[h * HD_ + d], rpe_w[d * 8 + u], s);
        lk[(h * P_ + p) * 8 + u] = s;
    }
}

// ---------------------------------------------------------------------------
// prep2: biasT[h][j][p] = lk[h][p][rp_bucket[p][jm(j)]]
// ---------------------------------------------------------------------------
__global__ __launch_bounds__(256) void prep2_kernel(
    const float* __restrict__ lk, const int* __restrict__ rp_bucket,
    float* __restrict__ biasT)
{
    int bx = blockIdx.x;
    int h = bx / N_, j = bx % N_;
    int t = threadIdx.x;
    if (t >= PPAD) return;
    int jm;
    if (j == 0) jm = 0;
    else { jm = j - 1; if (jm >= 196) jm -= 196; jm += 1; }
    float v = 0.f;
    if (t < P_) {
        int bucket = rp_bucket[t * P_ + jm];
        v = lk[(h * P_ + t) * 8 + bucket];
    }
    biasT[((size_t)h * BIAS_N + j) * PPAD + t] = v;
}

// ---------------------------------------------------------------------------
// Templated 128x128x64 bf16 MFMA GEMM (unchanged from round 2)
// ---------------------------------------------------------------------------
template <bool F32OUT>
__global__ __launch_bounds__(256) void gemm_bf16(
    const u16* __restrict__ A, const u16* __restrict__ Bw,
    u16* __restrict__ Cb, float* __restrict__ Cf, const float* __restrict__ bias,
    int M, int ldc)
{
    __shared__ __align__(16) u16 As[128 * 64];
    __shared__ __align__(16) u16 Bs[128 * 64];
    const int n0 = blockIdx.x * 128, m0 = blockIdx.y * 128;
    const int t = threadIdx.x;
    const int w = t >> 6, l = t & 63;
    const int wr = w >> 1, wc = w & 1;
    const int l15 = l & 15, lg = l >> 4;
    const int Mc = M - 1;

    f32x4 acc[4][4];
    #pragma unroll
    for (int i = 0; i < 4; ++i)
        #pragma unroll
        for (int j = 0; j < 4; ++j) acc[i][j] = (f32x4){0.f, 0.f, 0.f, 0.f};

    int aoff[4][2], boff[4][2];
    #pragma unroll
    for (int mf = 0; mf < 4; ++mf)
        #pragma unroll
        for (int kk = 0; kk < 2; ++kk) {
            int row = wr * 64 + mf * 16 + l15;
            int s = kk * 4 + lg;
            aoff[mf][kk] = row * 64 + ((s ^ (row & 7)) << 3);
            row = wc * 64 + mf * 16 + l15;
            boff[mf][kk] = row * 64 + ((s ^ (row & 7)) << 3);
        }
    int srow[4], sslot[4], soff[4];
    #pragma unroll
    for (int i = 0; i < 4; ++i) {
        int c = t + 256 * i;
        srow[i] = c >> 3;
        sslot[i] = c & 7;
        soff[i] = srow[i] * 64 + ((sslot[i] ^ (srow[i] & 7)) << 3);
    }

    for (int ks = 0; ks < 12; ++ks) {
        const int k0 = ks * 64;
        bf16x8 ra[4], rb[4];
        #pragma unroll
        for (int i = 0; i < 4; ++i) {
            int am = m0 + srow[i]; if (am > Mc) am = Mc;
            ra[i] = *(const bf16x8*)(A + (size_t)am * 768 + k0 + sslot[i] * 8);
            rb[i] = *(const bf16x8*)(Bw + (size_t)(n0 + srow[i]) * 768 + k0 + sslot[i] * 8);
        }
        __syncthreads();
        #pragma unroll
        for (int i = 0; i < 4; ++i) {
            *(bf16x8*)(As + soff[i]) = ra[i];
            *(bf16x8*)(Bs + soff[i]) = rb[i];
        }
        __syncthreads();
        #pragma unroll
        for (int kk = 0; kk < 2; ++kk) {
            bf16x8 af[4], bf[4];
            #pragma unroll
            for (int mf = 0; mf < 4; ++mf) {
                af[mf] = *(const bf16x8*)(As + aoff[mf][kk]);
                bf[mf] = *(const bf16x8*)(Bs + boff[mf][kk]);
            }
            #pragma unroll
            for (int mf = 0; mf < 4; ++mf)
                #pragma unroll
                for (int nf = 0; nf < 4; ++nf)
                    acc[mf][nf] = __builtin_amdgcn_mfma_f32_16x16x32_bf16(
                        af[mf], bf[nf], acc[mf][nf], 0, 0, 0);
        }
    }

    #pragma unroll
    for (int mf = 0; mf < 4; ++mf) {
        #pragma unroll
        for (int nf = 0; nf < 4; ++nf) {
            int col = n0 + wc * 64 + nf * 16 + l15;
            float bb = 0.f;
            if (F32OUT) bb = bias[col];
            #pragma unroll
            for (int r = 0; r < 4; ++r) {
                int m = m0 + wr * 64 + mf * 16 + lg * 4 + r;
                if (m < M) {
                    if (F32OUT) Cf[(size_t)m * ldc + col] = acc[mf][nf][r] + bb;
                    else        Cb[(size_t)m * ldc + col] = f2bf(acc[mf][nf][r]);
                }
            }
        }
    }
}

// ---------------------------------------------------------------------------
// vtrans: Vt[b][h][d][j(448)] = KV[b*393+j][768 + h*64 + d]  (j>=393 -> 0)
// ---------------------------------------------------------------------------
__global__ __launch_bounds__(256) void vtrans_kernel(const u16* __restrict__ KV,
                                                     u16* __restrict__ Vt)
{
    const int bh = blockIdx.x;
    const int b = bh / H_, h = bh % H_;
    const int t = threadIdx.x, w = t >> 6, l = t & 63;
    const int d = w * 16 + (l >> 2);
    const int c = l & 3;
    const u16* src = KV + (size_t)b * N_ * 1536 + 768 + h * HD_ + d;
    u16* dst = Vt + (size_t)(bh * HD_ + d) * VTP;
    for (int jb = 0; jb < VTP; jb += 32) {
        int j0 = jb + c * 8;
        u16 v[8];
        #pragma unroll
        for (int i = 0; i < 8; ++i) {
            int j = j0 + i;
            v[i] = (j < N_) ? src[(size_t)j * 1536] : (u16)0;
        }
        *(bf16x8*)(dst + j0) = *(bf16x8*)v;
    }
}

// ---------------------------------------------------------------------------
// attention v2: block = (b, h, 64-row p-tile); 4 waves x 16 rows.
// K/V tiles staged in swizzled LDS shared by all waves; scores in registers;
// in-register softmax; P via LDS (pitch 456); 2-phase staging pipeline.
// grid: 3072 (XCD-swizzled), block 256
// ---------------------------------------------------------------------------
__global__ __launch_bounds__(256, 2) void attn_mfma2(
    const u16* __restrict__ qh, const u16* __restrict__ KV,
    const u16* __restrict__ Vt, const float* __restrict__ biasT,
    u16* __restrict__ Obuf)
{
    __shared__ __align__(16) u16 pts[64 * 456];   // 58368 B
    __shared__ __align__(16) u16 kvs[64 * 64];    //  8192 B

    // bijective XCD swizzle: siblings (same b,h) land on one XCD
    const int id = blockIdx.x;
    const int work = (id & 7) * 384 + (id >> 3);
    const int ptile = work & 3;
    const int rest = work >> 2;
    const int h = rest % 12;
    const int b = rest / 12;
    const int p0 = ptile * 64;

    const int t = threadIdx.x, w = t >> 6, l = t & 63;
    const int l15 = l & 15, lg = l >> 4;
    const int p0w = p0 + w * 16;

    // staging geometry: 2 chunks/thread, linear global -> swizzled LDS
    int srow[2], sslot[2], swoff[2];
    #pragma unroll
    for (int i = 0; i < 2; ++i) {
        int c = t + 256 * i;
        srow[i] = c >> 3; sslot[i] = c & 7;
        swoff[i] = srow[i] * 64 + ((sslot[i] ^ (srow[i] & 7)) << 3);
    }

    // Q fragments (row-clamped)
    int prow = p0w + l15; if (prow > P_ - 1) prow = P_ - 1;
    const u16* qp = qh + (size_t)prow * C_ + h * HD_ + lg * 8;
    bf16x8 qf0 = *(const bf16x8*)(qp);
    bf16x8 qf1 = *(const bf16x8*)(qp + 32);

    const u16* Kbase = KV + (size_t)b * (N_ * 1536) + h * HD_;
    const u16* Vbase = Vt + (size_t)(b * H_ + h) * (HD_ * VTP);

    f32x4 acc[7][4];
    #pragma unroll
    for (int i = 0; i < 7; ++i)
        #pragma unroll
        for (int j = 0; j < 4; ++j) acc[i][j] = (f32x4){0.f, 0.f, 0.f, 0.f};

    // ---------------- pass 1: QK^T ----------------
    bf16x8 ra[2];
    #pragma unroll
    for (int i = 0; i < 2; ++i)
        ra[i] = *(const bf16x8*)(Kbase + (size_t)srow[i] * 1536 + sslot[i] * 8);
    #pragma unroll
    for (int i = 0; i < 2; ++i) *(bf16x8*)(kvs + swoff[i]) = ra[i];
    __syncthreads();

    #pragma unroll
    for (int nt = 0; nt < 7; ++nt) {
        if (nt < 6) {
            #pragma unroll
            for (int i = 0; i < 2; ++i) {
                int rn = (nt + 1) * 64 + srow[i]; if (rn > N_ - 1) rn = N_ - 1;
                ra[i] = *(const bf16x8*)(Kbase + (size_t)rn * 1536 + sslot[i] * 8);
            }
        }
        __builtin_amdgcn_s_setprio(1);
        #pragma unroll
        for (int kc = 0; kc < 2; ++kc) {
            #pragma unroll
            for (int sub = 0; sub < 4; ++sub) {
                int row = sub * 16 + l15;
                bf16x8 kb = *(const bf16x8*)(kvs + row * 64 + (((kc * 4 + lg) ^ (row & 7)) << 3));
                acc[nt][sub] = __builtin_amdgcn_mfma_f32_16x16x32_bf16(
                    kc ? qf1 : qf0, kb, acc[nt][sub], 0, 0, 0);
            }
        }
        __builtin_amdgcn_s_setprio(0);
        __syncthreads();
        if (nt < 6) {
            #pragma unroll
            for (int i = 0; i < 2; ++i) *(bf16x8*)(kvs + swoff[i]) = ra[i];
            __syncthreads();
        }
    }

    // ---------------- bias + scale + n-mask ----------------
    const int pcl = (p0w + lg * 4) > (PPAD - 4) ? (PPAD - 4) : (p0w + lg * 4);
    #pragma unroll
    for (int nt = 0; nt < 7; ++nt) {
        #pragma unroll
        for (int sub = 0; sub < 4; ++sub) {
            int n = nt * 64 + sub * 16 + l15;
            int jc = n > N_ - 1 ? N_ - 1 : n;
            float4 b4 = *(const float4*)(biasT + ((size_t)h * BIAS_N + jc) * PPAD + pcl);
            if (n < N_) {
                f32x4 bv = (f32x4){b4.x, b4.y, b4.z, b4.w};
                acc[nt][sub] = acc[nt][sub] * SCALE_ + bv;
            } else {
                acc[nt][sub] = (f32x4){-1e30f, -1e30f, -1e30f, -1e30f};
            }
        }
    }

    // ---------------- in-register softmax (row p = p0w + lg*4 + r) ----------
    float rinv4[4];
    #pragma unroll
    for (int r = 0; r < 4; ++r) {
        float m = -1e30f;
        #pragma unroll
        for (int nt = 0; nt < 7; ++nt)
            #pragma unroll
            for (int sub = 0; sub < 4; ++sub)
                m = fmaxf(m, acc[nt][sub][r]);
        m = fmaxf(m, __shfl_xor(m, 1));
        m = fmaxf(m, __shfl_xor(m, 2));
        m = fmaxf(m, __shfl_xor(m, 4));
        m = fmaxf(m, __shfl_xor(m, 8));
        float s = 0.f;
        #pragma unroll
        for (int nt = 0; nt < 7; ++nt)
            #pragma unroll
            for (int sub = 0; sub < 4; ++sub) {
                float e = __expf(acc[nt][sub][r] - m);
                acc[nt][sub][r] = e;
                s += e;
            }
        s += __shfl_xor(s, 1); s += __shfl_xor(s, 2);
        s += __shfl_xor(s, 4); s += __shfl_xor(s, 8);
        rinv4[r] = 1.0f / s;
    }

    // ---------------- P -> LDS bf16 ----------------
    #pragma unroll
    for (int nt = 0; nt < 7; ++nt)
        #pragma unroll
        for (int sub = 0; sub < 4; ++sub)
            #pragma unroll
            for (int r = 0; r < 4; ++r)
                pts[(w * 16 + lg * 4 + r) * 456 + nt * 64 + sub * 16 + l15] =
                    f2bf(acc[nt][sub][r] * rinv4[r]);
    __syncthreads();

    // ---------------- pass 2: PV ----------------
    f32x4 o[4];
    #pragma unroll
    for (int i = 0; i < 4; ++i) o[i] = (f32x4){0.f, 0.f, 0.f, 0.f};

    #pragma unroll
    for (int i = 0; i < 2; ++i)
        ra[i] = *(const bf16x8*)(Vbase + (size_t)srow[i] * VTP + sslot[i] * 8);
    #pragma unroll
    for (int i = 0; i < 2; ++i) *(bf16x8*)(kvs + swoff[i]) = ra[i];
    __syncthreads();

    #pragma unroll
    for (int nt = 0; nt < 7; ++nt) {
        if (nt < 6) {
            #pragma unroll
            for (int i = 0; i < 2; ++i)
                ra[i] = *(const bf16x8*)(Vbase + (size_t)srow[i] * VTP + (nt + 1) * 64 + sslot[i] * 8);
        }
        __builtin_amdgcn_s_setprio(1);
        #pragma unroll
        for (int kc = 0; kc < 2; ++kc) {
            bf16x8 pa = *(const bf16x8*)(pts + (w * 16 + l15) * 456 + nt * 64 + kc * 32 + lg * 8);
            #pragma unroll
            for (int dsub = 0; dsub < 4; ++dsub) {
                int row = dsub * 16 + l15;
                bf16x8 vb = *(const bf16x8*)(kvs + row * 64 + (((kc * 4 + lg) ^ (row & 7)) << 3));
                o[dsub] = __builtin_amdgcn_mfma_f32_16x16x32_bf16(pa, vb, o[dsub], 0, 0, 0);
            }
        }
        __builtin_amdgcn_s_setprio(0);
        __syncthreads();
        if (nt < 6) {
            #pragma unroll
            for (int i = 0; i < 2; ++i) *(bf16x8*)(kvs + swoff[i]) = ra[i];
            __syncthreads();
        }
    }

    // ---------------- store ----------------
    #pragma unroll
    for (int dsub = 0; dsub < 4; ++dsub)
        #pragma unroll
        for (int r = 0; r < 4; ++r) {
            int p = p0w + lg * 4 + r;
            if (p < P_)
                Obuf[((size_t)b * P_ + p) * C_ + h * HD_ + dsub * 16 + l15] = f2bf(o[dsub][r]);
        }
}

// ---------------------------------------------------------------------------
extern "C" void kernel_launch(void* const* d_in, const int* in_sizes, int n_in,
                              void* d_out, int out_size, void* d_ws, size_t ws_size,
                              hipStream_t stream)
{
    const float* x         = (const float*)d_in[0];
    const float* q_learned = (const float*)d_in[1];
    const float* pos_embed = (const float*)d_in[2];
    const float* wk        = (const float*)d_in[3];
    const float* wv        = (const float*)d_in[4];
    const float* rpe_w     = (const float*)d_in[5];
    const float* proj_w    = (const float*)d_in[6];
    const float* proj_b    = (const float*)d_in[7];
    const int*   rp_bucket = (const int*)d_in[8];
    float* out = (float*)d_out;

    char* ws = (char*)d_ws;
    u16*   xh    = (u16*)(ws);                        // 38,633,472 B
    u16*   wkvh  = (u16*)(ws + 38633472);             //  2,359,296 B
    u16*   pwh   = (u16*)(ws + 40992768);             //  1,179,648 B
    u16*   qh    = (u16*)(ws + 42172416);             //    302,592 B
    float* lk    = (float*)(ws + 42475008);           //     75,776 B
    float* biasT = (float*)(ws + 42550784);           //  4,153,344 B
    u16*   KV    = (u16*)(ws + 46704128);             // 77,266,944 B
    u16*   Vt    = (u16*)(ws + 123971072);            // 44,040,192 B
    u16*   Obuf  = (u16*)(ws + 168011264);            // 19,365,888 B (end ~179 MB)

    f2bf_kernel<<<(19316736 / 4 + 255) / 256, 256, 0, stream>>>(x, xh, 19316736 / 4);
    f2bf_kernel<<<(589824 / 4 + 255) / 256, 256, 0, stream>>>(wk, wkvh, 589824 / 4);
    f2bf_kernel<<<(589824 / 4 + 255) / 256, 256, 0, stream>>>(wv, wkvh + 589824, 589824 / 4);
    f2bf_kernel<<<(589824 / 4 + 255) / 256, 256, 0, stream>>>(proj_w, pwh, 589824 / 4);

    prep1_kernel<<<P_, 256, 0, stream>>>(q_learned, pos_embed, rpe_w, qh, lk);
    prep2_kernel<<<H_ * N_, 256, 0, stream>>>(lk, rp_bucket, biasT);

    dim3 gkv(1536 / 128, (M_KV + 127) / 128);
    gemm_bf16<false><<<gkv, 256, 0, stream>>>(xh, wkvh, KV, nullptr, nullptr, M_KV, 1536);

    vtrans_kernel<<<B_ * H_, 256, 0, stream>>>(KV, Vt);

    attn_mfma2<<<3072, 256, 0, stream>>>(qh, KV, Vt, biasT, Obuf);

    dim3 gpr(768 / 128, (M_PR + 127) / 128);
    gemm_bf16<true><<<gpr, 256, 0, stream>>>(Obuf, pwh, nullptr, out, proj_b, M_PR, 768);
}

// Round 4
// 252.885 us; speedup vs baseline: 9.9218x; 1.0998x over previous
//
#include <hip/hip_runtime.h>

typedef unsigned short u16;
typedef short bf16x8 __attribute__((ext_vector_type(8)));
typedef float f32x4 __attribute__((ext_vector_type(4)));
typedef const __attribute__((address_space(1))) void* gptr_t;
typedef __attribute__((address_space(3))) void* lptr_t;

#define B_   64
#define N_   393
#define C_   768
#define H_   12
#define HD_  64
#define P_   197
#define BIAS_N 416
#define PPAD 208
#define VTP  448
#define M_KV (B_ * N_)   // 25152
#define M_PR (B_ * P_)   // 12608
#define SCALE_ 0.125f

__device__ __forceinline__ u16 f2bf(float f) {
    unsigned u = __float_as_uint(f);
    return (u16)((u + 0x7FFFu + ((u >> 16) & 1u)) >> 16);
}

// ---------------------------------------------------------------------------
// fp32 -> bf16 conversion (vectorized, n % 4 == 0)
// ---------------------------------------------------------------------------
__global__ __launch_bounds__(256) void f2bf_kernel(const float* __restrict__ in,
                                                   u16* __restrict__ out, int n4) {
    int i = blockIdx.x * 256 + threadIdx.x;
    if (i < n4) {
        float4 v = ((const float4*)in)[i];
        u16 o[4] = {f2bf(v.x), f2bf(v.y), f2bf(v.z), f2bf(v.w)};
        *(uint2*)(out + i * 4) = *(uint2*)o;
    }
}

// fused conversion of wk, wv, proj_w (each 589824 elems = 576 blocks of 256x4)
__global__ __launch_bounds__(256) void convw_kernel(
    const float* __restrict__ wk, const float* __restrict__ wv,
    const float* __restrict__ pw, u16* __restrict__ wkvh, u16* __restrict__ pwh) {
    int sec = blockIdx.x / 576;
    int i = (blockIdx.x % 576) * 256 + threadIdx.x;
    const float* src = sec == 0 ? wk : (sec == 1 ? wv : pw);
    u16* dst = sec == 0 ? wkvh : (sec == 1 ? wkvh + 589824 : pwh);
    float4 v = ((const float4*)src)[i];
    u16 o[4] = {f2bf(v.x), f2bf(v.y), f2bf(v.z), f2bf(v.w)};
    *(uint2*)(dst + i * 4) = *(uint2*)o;
}

// ---------------------------------------------------------------------------
// prep1: q = q_learned + pos_embed -> qh (bf16 [P][C]); lk[h][p][8] fp32
// ---------------------------------------------------------------------------
__global__ __launch_bounds__(256) void prep1_kernel(
    const float* __restrict__ q_learned, const float* __restrict__ pos_embed,
    const float* __restrict__ rpe_w, u16* __restrict__ qh, float* __restrict__ lk)
{
    __shared__ float q_s[C_];
    const int p = blockIdx.x, t = threadIdx.x;
    for (int c = t; c < C_; c += 256) {
        float v = q_learned[c] + pos_embed[p * C_ + c];
        q_s[c] = v;
        qh[p * C_ + c] = f2bf(v);
    }
    __syncthreads();
    if (t < H_ * 8) {
        int h = t >> 3, u = t & 7;
        float s = 0.f;
        #pragma unroll 8
        for (int d = 0; d < HD_; ++d)
            s = fmaf(q_s[h * HD_ + d], rpe_w[d * 8 + u], s);
        lk[(h * P_ + p) * 8 + u] = s;
    }
}

// ---------------------------------------------------------------------------
// prep2: biasT[h][j][p] = lk[h][p][rp_bucket[p][jm(j)]]
// ---------------------------------------------------------------------------
__global__ __launch_bounds__(256) void prep2_kernel(
    const float* __restrict__ lk, const int* __restrict__ rp_bucket,
    float* __restrict__ biasT)
{
    int bx = blockIdx.x;
    int h = bx / N_, j = bx % N_;
    int t = threadIdx.x;
    if (t >= PPAD) return;
    int jm;
    if (j == 0) jm = 0;
    else { jm = j - 1; if (jm >= 196) jm -= 196; jm += 1; }
    float v = 0.f;
    if (t < P_) {
        int bucket = rp_bucket[t * P_ + jm];
        v = lk[(h * P_ + t) * 8 + bucket];
    }
    biasT[((size_t)h * BIAS_N + j) * PPAD + t] = v;
}

// ---------------------------------------------------------------------------
// Templated 128x128x64 bf16 MFMA GEMM, m97 structure:
// global_load_lds(16B) direct staging into linear LDS [128][64],
// 2-barrier K-loop, bijective XCD swizzle (m204).
// grid: gx = N/128 (fast), gy = ceil(M/128). block 256 (4 waves, 2x2).
// ---------------------------------------------------------------------------
template <bool F32OUT>
__global__ __launch_bounds__(256) void gemm_bf16(
    const u16* __restrict__ A, const u16* __restrict__ Bw,
    u16* __restrict__ Cb, float* __restrict__ Cf, const float* __restrict__ bias,
    int M, int ldc)
{
    __shared__ __align__(16) u16 As[128 * 64];
    __shared__ __align__(16) u16 Bs[128 * 64];

    // bijective XCD remap: each XCD gets a contiguous chunk of work ids
    const int gx = gridDim.x;
    const int nwg = gx * gridDim.y;
    const int orig = blockIdx.y * gx + blockIdx.x;
    const int xcd = orig & 7, rank = orig >> 3;
    const int q = nwg >> 3, r = nwg & 7;
    const int wgid = (xcd < r ? xcd * (q + 1) : r * (q + 1) + (xcd - r) * q) + rank;
    const int n0 = (wgid % gx) * 128;
    const int m0 = (wgid / gx) * 128;

    const int t = threadIdx.x;
    const int w = t >> 6, l = t & 63;
    const int wr = w >> 1, wc = w & 1;
    const int l15 = l & 15, lg = l >> 4;
    const int lrow = l >> 3, lslot = l & 7;
    const int Mc = M - 1;

    f32x4 acc[4][4];
    #pragma unroll
    for (int i = 0; i < 4; ++i)
        #pragma unroll
        for (int j = 0; j < 4; ++j) acc[i][j] = (f32x4){0.f, 0.f, 0.f, 0.f};

    for (int ks = 0; ks < 12; ++ks) {
        const int k0 = ks * 64;
        if (ks) __syncthreads();          // previous tile fully consumed
        #pragma unroll
        for (int i = 0; i < 4; ++i) {
            const int rbase = w * 32 + i * 8;        // 8 rows per issue
            int arow = m0 + rbase + lrow; if (arow > Mc) arow = Mc;
            const int brow = n0 + rbase + lrow;
            const u16* ga = A  + (size_t)arow * 768 + k0 + lslot * 8;
            const u16* gb = Bw + (size_t)brow * 768 + k0 + lslot * 8;
            __builtin_amdgcn_global_load_lds((gptr_t)(const void*)ga,
                                             (lptr_t)(void*)(As + rbase * 64), 16, 0, 0);
            __builtin_amdgcn_global_load_lds((gptr_t)(const void*)gb,
                                             (lptr_t)(void*)(Bs + rbase * 64), 16, 0, 0);
        }
        __syncthreads();                  // drains vmcnt: tile resident
        #pragma unroll
        for (int kk = 0; kk < 2; ++kk) {
            bf16x8 af[4], bfr[4];
            #pragma unroll
            for (int mf = 0; mf < 4; ++mf) {
                af[mf]  = *(const bf16x8*)(As + (wr * 64 + mf * 16 + l15) * 64 + (kk * 4 + lg) * 8);
                bfr[mf] = *(const bf16x8*)(Bs + (wc * 64 + mf * 16 + l15) * 64 + (kk * 4 + lg) * 8);
            }
            #pragma unroll
            for (int mf = 0; mf < 4; ++mf)
                #pragma unroll
                for (int nf = 0; nf < 4; ++nf)
                    acc[mf][nf] = __builtin_amdgcn_mfma_f32_16x16x32_bf16(
                        af[mf], bfr[nf], acc[mf][nf], 0, 0, 0);
        }
    }

    #pragma unroll
    for (int mf = 0; mf < 4; ++mf) {
        #pragma unroll
        for (int nf = 0; nf < 4; ++nf) {
            int col = n0 + wc * 64 + nf * 16 + l15;
            float bb = 0.f;
            if (F32OUT) bb = bias[col];
            #pragma unroll
            for (int r = 0; r < 4; ++r) {
                int m = m0 + wr * 64 + mf * 16 + lg * 4 + r;
                if (m < M) {
                    if (F32OUT) Cf[(size_t)m * ldc + col] = acc[mf][nf][r] + bb;
                    else        Cb[(size_t)m * ldc + col] = f2bf(acc[mf][nf][r]);
                }
            }
        }
    }
}

// ---------------------------------------------------------------------------
// vtrans: Vt[b][h][d][j(448)] = KV[b*393+j][768 + h*64 + d]  (j>=393 -> 0)
// ---------------------------------------------------------------------------
__global__ __launch_bounds__(256) void vtrans_kernel(const u16* __restrict__ KV,
                                                     u16* __restrict__ Vt)
{
    const int bh = blockIdx.x;
    const int b = bh / H_, h = bh % H_;
    const int t = threadIdx.x, w = t >> 6, l = t & 63;
    const int d = w * 16 + (l >> 2);
    const int c = l & 3;
    const u16* src = KV + (size_t)b * N_ * 1536 + 768 + h * HD_ + d;
    u16* dst = Vt + (size_t)(bh * HD_ + d) * VTP;
    for (int jb = 0; jb < VTP; jb += 32) {
        int j0 = jb + c * 8;
        u16 v[8];
        #pragma unroll
        for (int i = 0; i < 8; ++i) {
            int j = j0 + i;
            v[i] = (j < N_) ? src[(size_t)j * 1536] : (u16)0;
        }
        *(bf16x8*)(dst + j0) = *(bf16x8*)v;
    }
}

// ---------------------------------------------------------------------------
// attention v2 (unchanged from round 3): block = (b, h, 64-row p-tile).
// ---------------------------------------------------------------------------
__global__ __launch_bounds__(256, 2) void attn_mfma2(
    const u16* __restrict__ qh, const u16* __restrict__ KV,
    const u16* __restrict__ Vt, const float* __restrict__ biasT,
    u16* __restrict__ Obuf)
{
    __shared__ __align__(16) u16 pts[64 * 456];   // 58368 B
    __shared__ __align__(16) u16 kvs[64 * 64];    //  8192 B

    const int id = blockIdx.x;
    const int work = (id & 7) * 384 + (id >> 3);
    const int ptile = work & 3;
    const int rest = work >> 2;
    const int h = rest % 12;
    const int b = rest / 12;
    const int p0 = ptile * 64;

    const int t = threadIdx.x, w = t >> 6, l = t & 63;
    const int l15 = l & 15, lg = l >> 4;
    const int p0w = p0 + w * 16;

    int srow[2], sslot[2], swoff[2];
    #pragma unroll
    for (int i = 0; i < 2; ++i) {
        int c = t + 256 * i;
        srow[i] = c >> 3; sslot[i] = c & 7;
        swoff[i] = srow[i] * 64 + ((sslot[i] ^ (srow[i] & 7)) << 3);
    }

    int prow = p0w + l15; if (prow > P_ - 1) prow = P_ - 1;
    const u16* qp = qh + (size_t)prow * C_ + h * HD_ + lg * 8;
    bf16x8 qf0 = *(const bf16x8*)(qp);
    bf16x8 qf1 = *(const bf16x8*)(qp + 32);

    const u16* Kbase = KV + (size_t)b * (N_ * 1536) + h * HD_;
    const u16* Vbase = Vt + (size_t)(b * H_ + h) * (HD_ * VTP);

    f32x4 acc[7][4];
    #pragma unroll
    for (int i = 0; i < 7; ++i)
        #pragma unroll
        for (int j = 0; j < 4; ++j) acc[i][j] = (f32x4){0.f, 0.f, 0.f, 0.f};

    // ---------------- pass 1: QK^T ----------------
    bf16x8 ra[2];
    #pragma unroll
    for (int i = 0; i < 2; ++i)
        ra[i] = *(const bf16x8*)(Kbase + (size_t)srow[i] * 1536 + sslot[i] * 8);
    #pragma unroll
    for (int i = 0; i < 2; ++i) *(bf16x8*)(kvs + swoff[i]) = ra[i];
    __syncthreads();

    #pragma unroll
    for (int nt = 0; nt < 7; ++nt) {
        if (nt < 6) {
            #pragma unroll
            for (int i = 0; i < 2; ++i) {
                int rn = (nt + 1) * 64 + srow[i]; if (rn > N_ - 1) rn = N_ - 1;
                ra[i] = *(const bf16x8*)(Kbase + (size_t)rn * 1536 + sslot[i] * 8);
            }
        }
        __builtin_amdgcn_s_setprio(1);
        #pragma unroll
        for (int kc = 0; kc < 2; ++kc) {
            #pragma unroll
            for (int sub = 0; sub < 4; ++sub) {
                int row = sub * 16 + l15;
                bf16x8 kb = *(const bf16x8*)(kvs + row * 64 + (((kc * 4 + lg) ^ (row & 7)) << 3));
                acc[nt][sub] = __builtin_amdgcn_mfma_f32_16x16x32_bf16(
                    kc ? qf1 : qf0, kb, acc[nt][sub], 0, 0, 0);
            }
        }
        __builtin_amdgcn_s_setprio(0);
        __syncthreads();
        if (nt < 6) {
            #pragma unroll
            for (int i = 0; i < 2; ++i) *(bf16x8*)(kvs + swoff[i]) = ra[i];
            __syncthreads();
        }
    }

    // ---------------- bias + scale + n-mask ----------------
    const int pcl = (p0w + lg * 4) > (PPAD - 4) ? (PPAD - 4) : (p0w + lg * 4);
    #pragma unroll
    for (int nt = 0; nt < 7; ++nt) {
        #pragma unroll
        for (int sub = 0; sub < 4; ++sub) {
            int n = nt * 64 + sub * 16 + l15;
            int jc = n > N_ - 1 ? N_ - 1 : n;
            float4 b4 = *(const float4*)(biasT + ((size_t)h * BIAS_N + jc) * PPAD + pcl);
            if (n < N_) {
                f32x4 bv = (f32x4){b4.x, b4.y, b4.z, b4.w};
                acc[nt][sub] = acc[nt][sub] * SCALE_ + bv;
            } else {
                acc[nt][sub] = (f32x4){-1e30f, -1e30f, -1e30f, -1e30f};
            }
        }
    }

    // ---------------- in-register softmax ----------------
    float rinv4[4];
    #pragma unroll
    for (int r = 0; r < 4; ++r) {
        float m = -1e30f;
        #pragma unroll
        for (int nt = 0; nt < 7; ++nt)
            #pragma unroll
            for (int sub = 0; sub < 4; ++sub)
                m = fmaxf(m, acc[nt][sub][r]);
        m = fmaxf(m, __shfl_xor(m, 1));
        m = fmaxf(m, __shfl_xor(m, 2));
        m = fmaxf(m, __shfl_xor(m, 4));
        m = fmaxf(m, __shfl_xor(m, 8));
        float s = 0.f;
        #pragma unroll
        for (int nt = 0; nt < 7; ++nt)
            #pragma unroll
            for (int sub = 0; sub < 4; ++sub) {
                float e = __expf(acc[nt][sub][r] - m);
                acc[nt][sub][r] = e;
                s += e;
            }
        s += __shfl_xor(s, 1); s += __shfl_xor(s, 2);
        s += __shfl_xor(s, 4); s += __shfl_xor(s, 8);
        rinv4[r] = 1.0f / s;
    }

    // ---------------- P -> LDS bf16 ----------------
    #pragma unroll
    for (int nt = 0; nt < 7; ++nt)
        #pragma unroll
        for (int sub = 0; sub < 4; ++sub)
            #pragma unroll
            for (int r = 0; r < 4; ++r)
                pts[(w * 16 + lg * 4 + r) * 456 + nt * 64 + sub * 16 + l15] =
                    f2bf(acc[nt][sub][r] * rinv4[r]);
    __syncthreads();

    // ---------------- pass 2: PV ----------------
    f32x4 o[4];
    #pragma unroll
    for (int i = 0; i < 4; ++i) o[i] = (f32x4){0.f, 0.f, 0.f, 0.f};

    #pragma unroll
    for (int i = 0; i < 2; ++i)
        ra[i] = *(const bf16x8*)(Vbase + (size_t)srow[i] * VTP + sslot[i] * 8);
    #pragma unroll
    for (int i = 0; i < 2; ++i) *(bf16x8*)(kvs + swoff[i]) = ra[i];
    __syncthreads();

    #pragma unroll
    for (int nt = 0; nt < 7; ++nt) {
        if (nt < 6) {
            #pragma unroll
            for (int i = 0; i < 2; ++i)
                ra[i] = *(const bf16x8*)(Vbase + (size_t)srow[i] * VTP + (nt + 1) * 64 + sslot[i] * 8);
        }
        __builtin_amdgcn_s_setprio(1);
        #pragma unroll
        for (int kc = 0; kc < 2; ++kc) {
            bf16x8 pa = *(const bf16x8*)(pts + (w * 16 + l15) * 456 + nt * 64 + kc * 32 + lg * 8);
            #pragma unroll
            for (int dsub = 0; dsub < 4; ++dsub) {
                int row = dsub * 16 + l15;
                bf16x8 vb = *(const bf16x8*)(kvs + row * 64 + (((kc * 4 + lg) ^ (row & 7)) << 3));
                o[dsub] = __builtin_amdgcn_mfma_f32_16x16x32_bf16(pa, vb, o[dsub], 0, 0, 0);
            }
        }
        __builtin_amdgcn_s_setprio(0);
        __syncthreads();
        if (nt < 6) {
            #pragma unroll
            for (int i = 0; i < 2; ++i) *(bf16x8*)(kvs + swoff[i]) = ra[i];
            __syncthreads();
        }
    }

    // ---------------- store ----------------
    #pragma unroll
    for (int dsub = 0; dsub < 4; ++dsub)
        #pragma unroll
        for (int r = 0; r < 4; ++r) {
            int p = p0w + lg * 4 + r;
            if (p < P_)
                Obuf[((size_t)b * P_ + p) * C_ + h * HD_ + dsub * 16 + l15] = f2bf(o[dsub][r]);
        }
}

// ---------------------------------------------------------------------------
extern "C" void kernel_launch(void* const* d_in, const int* in_sizes, int n_in,
                              void* d_out, int out_size, void* d_ws, size_t ws_size,
                              hipStream_t stream)
{
    const float* x         = (const float*)d_in[0];
    const float* q_learned = (const float*)d_in[1];
    const float* pos_embed = (const float*)d_in[2];
    const float* wk        = (const float*)d_in[3];
    const float* wv        = (const float*)d_in[4];
    const float* rpe_w     = (const float*)d_in[5];
    const float* proj_w    = (const float*)d_in[6];
    const float* proj_b    = (const float*)d_in[7];
    const int*   rp_bucket = (const int*)d_in[8];
    float* out = (float*)d_out;

    char* ws = (char*)d_ws;
    u16*   xh    = (u16*)(ws);                        // 38,633,472 B
    u16*   wkvh  = (u16*)(ws + 38633472);             //  2,359,296 B
    u16*   pwh   = (u16*)(ws + 40992768);             //  1,179,648 B
    u16*   qh    = (u16*)(ws + 42172416);             //    302,592 B
    float* lk    = (float*)(ws + 42475008);           //     75,776 B
    float* biasT = (float*)(ws + 42550784);           //  4,153,344 B
    u16*   KV    = (u16*)(ws + 46704128);             // 77,266,944 B
    u16*   Vt    = (u16*)(ws + 123971072);            // 44,040,192 B
    u16*   Obuf  = (u16*)(ws + 168011264);            // 19,365,888 B (end ~179 MB)

    f2bf_kernel<<<(19316736 / 4 + 255) / 256, 256, 0, stream>>>(x, xh, 19316736 / 4);
    convw_kernel<<<3 * 576, 256, 0, stream>>>(wk, wv, proj_w, wkvh, pwh);

    prep1_kernel<<<P_, 256, 0, stream>>>(q_learned, pos_embed, rpe_w, qh, lk);
    prep2_kernel<<<H_ * N_, 256, 0, stream>>>(lk, rp_bucket, biasT);

    dim3 gkv(1536 / 128, (M_KV + 127) / 128);   // 12 x 197
    gemm_bf16<false><<<gkv, 256, 0, stream>>>(xh, wkvh, KV, nullptr, nullptr, M_KV, 1536);

    vtrans_kernel<<<B_ * H_, 256, 0, stream>>>(KV, Vt);

    attn_mfma2<<<3072, 256, 0, stream>>>(qh, KV, Vt, biasT, Obuf);

    dim3 gpr(768 / 128, (M_PR + 127) / 128);    // 6 x 99
    gemm_bf16<true><<<gpr, 256, 0, stream>>>(Obuf, pwh, nullptr, out, proj_b, M_PR, 768);
}